// Round 7
// baseline (344.076 us; speedup 1.0000x reference)
//
#include <hip/hip_runtime.h>

// B=4, S=2048, D=1024, H=16, Dk=64.  M = B*S = 8192.
// cvt(fp32->bf16) -> proj GEMMs (r4-verified BK=32 swizzled 128^2 core;
// q/k [bh][s][dk], v^T sigma-permuted [bh][dk][s], q pre-scaled 0.125*log2e)
// -> flash attn v3 (dbuf K/Vt, XCD-local grid, qt=128 -> 4 blocks/CU)
// -> out GEMM (same core).  Workspace: 104 MB.
//
// LDS swizzle (r4-verified 0-conflict involution): 128B rows, 8 slots of
// 16B, slot = chunk ^ (row&7).  GLD16 keeps a LINEAR LDS dest (HW rule);
// the permutation is baked into the per-lane GLOBAL source address
// (src_chunk = (lane&7)^(lane>>3)); ds_read applies the same XOR.

typedef __bf16 bhalf_t;
typedef __attribute__((ext_vector_type(8)))  __bf16 bf16x8;
typedef __attribute__((ext_vector_type(4)))  __bf16 bf16x4;
typedef __attribute__((ext_vector_type(4)))  float  f32x4;
typedef __attribute__((ext_vector_type(16))) float  f32x16;

typedef __attribute__((address_space(1))) void gvoid_t;
typedef __attribute__((address_space(3))) void lvoid_t;
#define GLD16(g, l) __builtin_amdgcn_global_load_lds((const gvoid_t*)(g), (lvoid_t*)(l), 16, 0, 0)

// ---------------------------------------------------------------------------
__global__ __launch_bounds__(256) void cvt_all(
    const float* __restrict__ Q, const float* __restrict__ Kin, const float* __restrict__ V,
    const float* __restrict__ Wq, const float* __restrict__ Wk, const float* __restrict__ Wv,
    const float* __restrict__ Wo,
    bhalf_t* __restrict__ Qb, bhalf_t* __restrict__ Kb, bhalf_t* __restrict__ Vb,
    bhalf_t* __restrict__ Wqb, bhalf_t* __restrict__ Wkb, bhalf_t* __restrict__ Wvb,
    bhalf_t* __restrict__ Wob)
{
  size_t t = (size_t)blockIdx.x * 256 + threadIdx.x;   // float4 index
  const float* src; bhalf_t* dst;
  if (t < 2097152)      { src = Q;   dst = Qb; }
  else if (t < 4194304) { src = Kin; dst = Kb; t -= 2097152; }
  else if (t < 6291456) { src = V;   dst = Vb; t -= 4194304; }
  else {
    t -= 6291456;
    int w = (int)(t >> 18); t &= 262143;
    src = (w == 0) ? Wq  : (w == 1) ? Wk  : (w == 2) ? Wv  : Wo;
    dst = (w == 0) ? Wqb : (w == 1) ? Wkb : (w == 2) ? Wvb : Wob;
  }
  float4 f = ((const float4*)src)[t];
  bf16x4 o;
  o.x = (bhalf_t)f.x; o.y = (bhalf_t)f.y; o.z = (bhalf_t)f.z; o.w = (bhalf_t)f.w;
  ((bf16x4*)dst)[t] = o;
}

// ---------------------------------------------------------------------------
// r4-verified swizzled BK=32 core: C[128x128] tile of A[M,1024] @ B^T.
// ---------------------------------------------------------------------------
__device__ __forceinline__ void gemm_core_128_swz(
    const bhalf_t* __restrict__ A, const bhalf_t* __restrict__ B,
    int bm, int bn, bhalf_t* As, bhalf_t* Bs, f32x4 acc[4][4])
{
  const int tid = threadIdx.x, lane = tid & 63, wave = tid >> 6;
  const int wm = wave >> 1, wn = wave & 1;
  const int quad = lane >> 4, tn = lane & 15;

  const int u    = (lane & 7) ^ (lane >> 3);
  const int roff = (lane >> 3) + 64 * (u >> 2);
  const int gk   = (u & 3) * 8;

  const bhalf_t* Ag0 = A + (size_t)(bm * 128 + wave * 8 + roff) * 1024 + gk;
  const bhalf_t* Ag1 = A + (size_t)(bm * 128 + (wave + 4) * 8 + roff) * 1024 + gk;
  const bhalf_t* Bg0 = B + (size_t)(bn * 128 + wave * 8 + roff) * 1024 + gk;
  const bhalf_t* Bg1 = B + (size_t)(bn * 128 + (wave + 4) * 8 + roff) * 1024 + gk;
  bhalf_t* Ad0 = As + wave * 512;  bhalf_t* Ad1 = As + (wave + 4) * 512;
  bhalf_t* Bd0 = Bs + wave * 512;  bhalf_t* Bd1 = Bs + (wave + 4) * 512;

  const int aswz = ((wm * 4 + quad) ^ (tn & 7)) * 8;
  const int bswz = ((wn * 4 + quad) ^ (tn & 7)) * 8;

  for (int k0 = 0; k0 < 1024; k0 += 32) {
    GLD16(Ag0 + k0, Ad0);
    GLD16(Ag1 + k0, Ad1);
    GLD16(Bg0 + k0, Bd0);
    GLD16(Bg1 + k0, Bd1);
    __syncthreads();
    bf16x8 af[4], bfr[4];
#pragma unroll
    for (int i = 0; i < 4; ++i)
      af[i] = *(const bf16x8*)(As + (i * 16 + tn) * 64 + aswz);
#pragma unroll
    for (int j = 0; j < 4; ++j)
      bfr[j] = *(const bf16x8*)(Bs + (j * 16 + tn) * 64 + bswz);
#pragma unroll
    for (int i = 0; i < 4; ++i)
#pragma unroll
      for (int j = 0; j < 4; ++j)
        acc[i][j] = __builtin_amdgcn_mfma_f32_16x16x32_bf16(af[i], bfr[j], acc[i][j], 0, 0, 0);
    __syncthreads();
  }
}

// ---------------------------------------------------------------------------
// Fused q/k/v projection (r4 structure).  q scaled by 0.125*log2e; v stored
// transposed [bh][dk][s] with s sigma-permuted (swap bits 2<->3).
// Block mapping: bm = idx&63 (fast) so XCD = bm%8 -> per-XCD A-slab reuse.
// ---------------------------------------------------------------------------
__global__ __launch_bounds__(256) void proj_gemm(
    const bhalf_t* __restrict__ Qb, const bhalf_t* __restrict__ Kb, const bhalf_t* __restrict__ Vb,
    const bhalf_t* __restrict__ Wqb, const bhalf_t* __restrict__ Wkb, const bhalf_t* __restrict__ Wvb,
    const float* __restrict__ bq, const float* __restrict__ bk, const float* __restrict__ bv,
    bhalf_t* __restrict__ qo, bhalf_t* __restrict__ ko, bhalf_t* __restrict__ vto)
{
  __shared__ bhalf_t As[4096];
  __shared__ bhalf_t Bs[4096];
  const int seg = blockIdx.x >> 9;
  const int idx = blockIdx.x & 511;
  const int bm = idx & 63, bn = idx >> 6;    // XCD-aware: bm fast-varying

  const bhalf_t *A, *Bw; const float* bias; bhalf_t* out; float scale; int mode;
  if (seg == 0)      { A = Qb; Bw = Wqb; bias = bq; out = qo;  scale = 0.18033688f; mode = 0; }
  else if (seg == 1) { A = Kb; Bw = Wkb; bias = bk; out = ko;  scale = 1.0f;        mode = 0; }
  else               { A = Vb; Bw = Wvb; bias = bv; out = vto; scale = 1.0f;        mode = 1; }

  f32x4 acc[4][4];
#pragma unroll
  for (int i = 0; i < 4; ++i)
#pragma unroll
    for (int j = 0; j < 4; ++j)
      acc[i][j] = (f32x4){0.f, 0.f, 0.f, 0.f};

  gemm_core_128_swz(A, Bw, bm, bn, As, Bs, acc);

  const int lane = threadIdx.x & 63, wave = threadIdx.x >> 6;
  const int wm = wave >> 1, wn = wave & 1, quad = lane >> 4, tn = lane & 15;
#pragma unroll
  for (int i = 0; i < 4; ++i)
#pragma unroll
    for (int j = 0; j < 4; ++j) {
      const int n = bn * 128 + wn * 64 + j * 16 + tn;
      const float bsv = bias[n];
      const int h = n >> 6, dk = n & 63;
#pragma unroll
      for (int r = 0; r < 4; ++r) {
        const int m = bm * 128 + wm * 64 + i * 16 + quad * 4 + r;
        const int b = m >> 11, s = m & 2047;
        const float v = (acc[i][j][r] + bsv) * scale;
        size_t addr;
        if (mode == 0) addr = (((size_t)(b * 16 + h)) * 2048 + s) * 64 + dk;
        else {
          const int s2 = (s & ~12) | ((s & 4) << 1) | ((s & 8) >> 1);  // sigma
          addr = (((size_t)(b * 16 + h)) * 64 + dk) * 2048 + s2;
        }
        out[addr] = (bhalf_t)v;
      }
    }
}

// ---------------------------------------------------------------------------
__global__ __launch_bounds__(256) void out_gemm(
    const bhalf_t* __restrict__ A, const bhalf_t* __restrict__ Bw,
    const float* __restrict__ bias, float* __restrict__ Cout)
{
  __shared__ bhalf_t As[4096];
  __shared__ bhalf_t Bs[4096];
  const int bm = blockIdx.x & 63, bn = blockIdx.x >> 6;   // XCD-aware

  f32x4 acc[4][4];
#pragma unroll
  for (int i = 0; i < 4; ++i)
#pragma unroll
    for (int j = 0; j < 4; ++j)
      acc[i][j] = (f32x4){0.f, 0.f, 0.f, 0.f};

  gemm_core_128_swz(A, Bw, bm, bn, As, Bs, acc);

  const int lane = threadIdx.x & 63, wave = threadIdx.x >> 6;
  const int wm = wave >> 1, wn = wave & 1, quad = lane >> 4, tn = lane & 15;
#pragma unroll
  for (int i = 0; i < 4; ++i)
#pragma unroll
    for (int j = 0; j < 4; ++j) {
      const int n = bn * 128 + wn * 64 + j * 16 + tn;
      const float bsv = bias[n];
#pragma unroll
      for (int r = 0; r < 4; ++r) {
        const int m = bm * 128 + wm * 64 + i * 16 + quad * 4 + r;
        Cout[(size_t)m * 1024 + n] = acc[i][j][r] + bsv;
      }
    }
}

// ---------------------------------------------------------------------------
// Flash attention v3, dbuf K/Vt (r5), XCD-local grid (r6), qt=128 (NEW):
// grid (64,16) = 1024 blocks = 4 blocks/CU (was 2) -> 4 waves/SIMD to hide
// the QK->exp2->pack->PV dependency chain.  Each wave owns 32 q rows (the
// old qs=0 path verbatim); K/V staged per block as before (16 sharers per
// bh, all XCD-co-resident -> L2 hits, mechanism verified r6).
// ---------------------------------------------------------------------------
__global__ __launch_bounds__(256, 4) void attn_kernel(
    const bhalf_t* __restrict__ qp, const bhalf_t* __restrict__ kp,
    const bhalf_t* __restrict__ vtp, bhalf_t* __restrict__ outp)
{
  __shared__ bhalf_t Klds[2][4096];    // [64 kv][64 dk], XOR-swizzled chunks
  __shared__ bhalf_t Vtlds[2][4096];   // [64 dk][64 kv(sigma)], XOR-swizzled

  const int tid = threadIdx.x, lane = tid & 63, wave = tid >> 6;
  const int q31 = lane & 31, h = lane >> 5;
  const int bh = blockIdx.x, qt = blockIdx.y;   // XCD = bh%8: K/V co-local

  // Q B-fragments for this wave's 32 q rows
  const bhalf_t* qbase = qp + (((size_t)bh * 2048) + qt * 128 + wave * 32 + q31) * 64;
  bf16x8 qf[4];
#pragma unroll
  for (int ks = 0; ks < 4; ++ks)
    qf[ks] = *(const bf16x8*)(qbase + ks * 16 + h * 8);

  f32x16 Ot[2];
#pragma unroll
  for (int dd = 0; dd < 2; ++dd)
#pragma unroll
    for (int i = 0; i < 16; ++i) Ot[dd][i] = 0.f;
  float Lp = 0.f;

  const bhalf_t* kbase  = kp  + (size_t)bh * 2048 * 64;
  const bhalf_t* vtbase = vtp + (size_t)bh * 64 * 2048;

  const int rloc = lane >> 3;                 // staging row within 8-row chunk
  const int cg8  = ((lane & 7) ^ rloc) * 8;   // swizzled source chunk (elems)
  const int q7 = q31 & 7;

  // prologue: stage tile 0 into buffer 0
#pragma unroll
  for (int i = 0; i < 2; ++i) {
    const int r0 = (wave * 2 + i) * 8;
    GLD16(kbase + (size_t)(r0 + rloc) * 64 + cg8, &Klds[0][r0 * 64]);
    GLD16(vtbase + (size_t)(r0 + rloc) * 2048 + cg8, &Vtlds[0][r0 * 64]);
  }
  __syncthreads();

  for (int kv0 = 0; kv0 < 2048; kv0 += 64) {
    const int cur = (kv0 >> 6) & 1, nxt = cur ^ 1;
    if (kv0 < 2048 - 64) {   // issue next tile early (hides under compute)
#pragma unroll
      for (int i = 0; i < 2; ++i) {
        const int r0 = (wave * 2 + i) * 8;
        GLD16(kbase + (size_t)(kv0 + 64 + r0 + rloc) * 64 + cg8, &Klds[nxt][r0 * 64]);
        GLD16(vtbase + (size_t)(r0 + rloc) * 2048 + (kv0 + 64) + cg8, &Vtlds[nxt][r0 * 64]);
      }
    }
    const bhalf_t* Kc = Klds[cur];
    const bhalf_t* Vc = Vtlds[cur];

    // S^T + exp2 + pack into PV B-fragments (register-only)
    bf16x8 pb[4];
#pragma unroll
    for (int mb = 0; mb < 2; ++mb) {
      bf16x8 ka[4];
#pragma unroll
      for (int ks = 0; ks < 4; ++ks)
        ka[ks] = *(const bf16x8*)(Kc + (mb * 32 + q31) * 64 + ((2 * ks + h) ^ q7) * 8);
      f32x16 S;
#pragma unroll
      for (int i = 0; i < 16; ++i) S[i] = 0.f;
#pragma unroll
      for (int ks = 0; ks < 4; ++ks)
        S = __builtin_amdgcn_mfma_f32_32x32x16_bf16(ka[ks], qf[ks], S, 0, 0, 0);
      float ls = 0.f;
#pragma unroll
      for (int half = 0; half < 2; ++half) {
        bf16x8 pk;
#pragma unroll
        for (int j = 0; j < 8; ++j) {
          const float e = __builtin_amdgcn_exp2f(S[half * 8 + j]);
          ls += e;
          pk[j] = (bhalf_t)e;
        }
        pb[mb * 2 + half] = pk;
      }
      Lp += ls;
    }

    // O^T += Vt @ P
#pragma unroll
    for (int dd = 0; dd < 2; ++dd)
#pragma unroll
      for (int kb = 0; kb < 4; ++kb) {
        const bf16x8 va = *(const bf16x8*)(Vc + (dd * 32 + q31) * 64 + ((2 * kb + h) ^ q7) * 8);
        Ot[dd] = __builtin_amdgcn_mfma_f32_32x32x16_bf16(va, pb[kb], Ot[dd], 0, 0, 0);
      }
    __syncthreads();   // drains vmcnt (next tile landed) + read-release of buf
  }

  // normalize (per-lane q) and store packed bf16x4
  const int b = bh >> 4, hh = bh & 15;
  const float Lt = Lp + __shfl_xor(Lp, 32, 64);
  const float linv = 1.0f / Lt;
  const int s = qt * 128 + wave * 32 + q31;
  bhalf_t* ob = outp + ((size_t)(b * 2048 + s)) * 1024 + hh * 64;
#pragma unroll
  for (int dd = 0; dd < 2; ++dd)
#pragma unroll
    for (int g = 0; g < 4; ++g) {
      bf16x4 o;
      o.x = (bhalf_t)(Ot[dd][4 * g + 0] * linv);
      o.y = (bhalf_t)(Ot[dd][4 * g + 1] * linv);
      o.z = (bhalf_t)(Ot[dd][4 * g + 2] * linv);
      o.w = (bhalf_t)(Ot[dd][4 * g + 3] * linv);
      *(bf16x4*)(ob + dd * 32 + g * 8 + h * 4) = o;
    }
}

// ---------------------------------------------------------------------------
extern "C" void kernel_launch(void* const* d_in, const int* in_sizes, int n_in,
                              void* d_out, int out_size, void* d_ws, size_t ws_size,
                              hipStream_t stream)
{
  const float* Q  = (const float*)d_in[0];
  const float* K  = (const float*)d_in[1];
  const float* V  = (const float*)d_in[2];
  const float* Wq = (const float*)d_in[3];
  const float* bq = (const float*)d_in[4];
  const float* Wk = (const float*)d_in[5];
  const float* bk = (const float*)d_in[6];
  const float* Wv = (const float*)d_in[7];
  const float* bv = (const float*)d_in[8];
  const float* Wo = (const float*)d_in[9];
  const float* bo = (const float*)d_in[10];

  char* ws = (char*)d_ws;
  const size_t SZ = 8192ull * 1024 * 2;   // 16 MB  [8192,1024] bf16
  const size_t WZ = 1024ull * 1024 * 2;   //  2 MB  [1024,1024] bf16
  bhalf_t* Qb   = (bhalf_t*)(ws);
  bhalf_t* Kb   = (bhalf_t*)(ws + SZ);
  bhalf_t* Vb   = (bhalf_t*)(ws + 2 * SZ);
  bhalf_t* Wqb  = (bhalf_t*)(ws + 3 * SZ);
  bhalf_t* Wkb  = (bhalf_t*)(ws + 3 * SZ + WZ);
  bhalf_t* Wvb  = (bhalf_t*)(ws + 3 * SZ + 2 * WZ);
  bhalf_t* Wob  = (bhalf_t*)(ws + 3 * SZ + 3 * WZ);
  bhalf_t* q_p  = (bhalf_t*)(ws + 3 * SZ + 4 * WZ);
  bhalf_t* k_p  = (bhalf_t*)(ws + 4 * SZ + 4 * WZ);
  bhalf_t* vt_p = (bhalf_t*)(ws + 5 * SZ + 4 * WZ);
  bhalf_t* attn_o = Qb;   // alias: Qb is dead after proj_gemm

  cvt_all<<<28672, 256, 0, stream>>>(Q, K, V, Wq, Wk, Wv, Wo,
                                     Qb, Kb, Vb, Wqb, Wkb, Wvb, Wob);
  proj_gemm<<<1536, 256, 0, stream>>>(Qb, Kb, Vb, Wqb, Wkb, Wvb,
                                      bq, bk, bv, q_p, k_p, vt_p);
  attn_kernel<<<dim3(64, 16), 256, 0, stream>>>(q_p, k_p, vt_p, attn_o);
  out_gemm<<<512, 256, 0, stream>>>(attn_o, Wob, bo, (float*)d_out);
}

// Round 8
// 341.423 us; speedup vs baseline: 1.0078x; 1.0078x over previous
//
#include <hip/hip_runtime.h>

// B=4, S=2048, D=1024, H=16, Dk=64.  M = B*S = 8192.
// cvt(fp32->bf16) -> proj GEMMs (r4-verified BK=32 swizzled 128^2 core;
// q/k [bh][s][dk], v^T sigma-permuted [bh][dk][s], q pre-scaled 0.125*log2e)
// -> flash attn v3 (dbuf K/Vt, XCD-local grid (64,8), qt=256, setprio on
// MFMA clusters) -> out GEMM (same core).  Workspace: 104 MB.
//
// LDS swizzle (r4-verified 0-conflict involution): 128B rows, 8 slots of
// 16B, slot = chunk ^ (row&7).  GLD16 keeps a LINEAR LDS dest (HW rule);
// the permutation is baked into the per-lane GLOBAL source address
// (src_chunk = (lane&7)^(lane>>3)); ds_read applies the same XOR.
//
// Attribution ledger: proj BK=64 (r6, +5), fp32-A sync (r3, +48) and async
// (r5, +43), 256^2 pipelined proj (r1/r2, +29/+36), attn qt=128 (r7, +20)
// all REFUTED; swizzle (r4, 0-conflict), attn dbuf (r5, -3), attn XCD-grid
// (r6, -7) VERIFIED.

typedef __bf16 bhalf_t;
typedef __attribute__((ext_vector_type(8)))  __bf16 bf16x8;
typedef __attribute__((ext_vector_type(4)))  __bf16 bf16x4;
typedef __attribute__((ext_vector_type(4)))  float  f32x4;
typedef __attribute__((ext_vector_type(16))) float  f32x16;

typedef __attribute__((address_space(1))) void gvoid_t;
typedef __attribute__((address_space(3))) void lvoid_t;
#define GLD16(g, l) __builtin_amdgcn_global_load_lds((const gvoid_t*)(g), (lvoid_t*)(l), 16, 0, 0)

// ---------------------------------------------------------------------------
__global__ __launch_bounds__(256) void cvt_all(
    const float* __restrict__ Q, const float* __restrict__ Kin, const float* __restrict__ V,
    const float* __restrict__ Wq, const float* __restrict__ Wk, const float* __restrict__ Wv,
    const float* __restrict__ Wo,
    bhalf_t* __restrict__ Qb, bhalf_t* __restrict__ Kb, bhalf_t* __restrict__ Vb,
    bhalf_t* __restrict__ Wqb, bhalf_t* __restrict__ Wkb, bhalf_t* __restrict__ Wvb,
    bhalf_t* __restrict__ Wob)
{
  size_t t = (size_t)blockIdx.x * 256 + threadIdx.x;   // float4 index
  const float* src; bhalf_t* dst;
  if (t < 2097152)      { src = Q;   dst = Qb; }
  else if (t < 4194304) { src = Kin; dst = Kb; t -= 2097152; }
  else if (t < 6291456) { src = V;   dst = Vb; t -= 4194304; }
  else {
    t -= 6291456;
    int w = (int)(t >> 18); t &= 262143;
    src = (w == 0) ? Wq  : (w == 1) ? Wk  : (w == 2) ? Wv  : Wo;
    dst = (w == 0) ? Wqb : (w == 1) ? Wkb : (w == 2) ? Wvb : Wob;
  }
  float4 f = ((const float4*)src)[t];
  bf16x4 o;
  o.x = (bhalf_t)f.x; o.y = (bhalf_t)f.y; o.z = (bhalf_t)f.z; o.w = (bhalf_t)f.w;
  ((bf16x4*)dst)[t] = o;
}

// ---------------------------------------------------------------------------
// r4-verified swizzled BK=32 core: C[128x128] tile of A[M,1024] @ B^T.
// ---------------------------------------------------------------------------
__device__ __forceinline__ void gemm_core_128_swz(
    const bhalf_t* __restrict__ A, const bhalf_t* __restrict__ B,
    int bm, int bn, bhalf_t* As, bhalf_t* Bs, f32x4 acc[4][4])
{
  const int tid = threadIdx.x, lane = tid & 63, wave = tid >> 6;
  const int wm = wave >> 1, wn = wave & 1;
  const int quad = lane >> 4, tn = lane & 15;

  const int u    = (lane & 7) ^ (lane >> 3);
  const int roff = (lane >> 3) + 64 * (u >> 2);
  const int gk   = (u & 3) * 8;

  const bhalf_t* Ag0 = A + (size_t)(bm * 128 + wave * 8 + roff) * 1024 + gk;
  const bhalf_t* Ag1 = A + (size_t)(bm * 128 + (wave + 4) * 8 + roff) * 1024 + gk;
  const bhalf_t* Bg0 = B + (size_t)(bn * 128 + wave * 8 + roff) * 1024 + gk;
  const bhalf_t* Bg1 = B + (size_t)(bn * 128 + (wave + 4) * 8 + roff) * 1024 + gk;
  bhalf_t* Ad0 = As + wave * 512;  bhalf_t* Ad1 = As + (wave + 4) * 512;
  bhalf_t* Bd0 = Bs + wave * 512;  bhalf_t* Bd1 = Bs + (wave + 4) * 512;

  const int aswz = ((wm * 4 + quad) ^ (tn & 7)) * 8;
  const int bswz = ((wn * 4 + quad) ^ (tn & 7)) * 8;

  for (int k0 = 0; k0 < 1024; k0 += 32) {
    GLD16(Ag0 + k0, Ad0);
    GLD16(Ag1 + k0, Ad1);
    GLD16(Bg0 + k0, Bd0);
    GLD16(Bg1 + k0, Bd1);
    __syncthreads();
    bf16x8 af[4], bfr[4];
#pragma unroll
    for (int i = 0; i < 4; ++i)
      af[i] = *(const bf16x8*)(As + (i * 16 + tn) * 64 + aswz);
#pragma unroll
    for (int j = 0; j < 4; ++j)
      bfr[j] = *(const bf16x8*)(Bs + (j * 16 + tn) * 64 + bswz);
#pragma unroll
    for (int i = 0; i < 4; ++i)
#pragma unroll
      for (int j = 0; j < 4; ++j)
        acc[i][j] = __builtin_amdgcn_mfma_f32_16x16x32_bf16(af[i], bfr[j], acc[i][j], 0, 0, 0);
    __syncthreads();
  }
}

// ---------------------------------------------------------------------------
// Fused q/k/v projection (r4 structure).  q scaled by 0.125*log2e; v stored
// transposed [bh][dk][s] with s sigma-permuted (swap bits 2<->3).
// Block mapping: bm = idx&63 (fast) so XCD = bm%8 -> per-XCD A-slab reuse.
// ---------------------------------------------------------------------------
__global__ __launch_bounds__(256) void proj_gemm(
    const bhalf_t* __restrict__ Qb, const bhalf_t* __restrict__ Kb, const bhalf_t* __restrict__ Vb,
    const bhalf_t* __restrict__ Wqb, const bhalf_t* __restrict__ Wkb, const bhalf_t* __restrict__ Wvb,
    const float* __restrict__ bq, const float* __restrict__ bk, const float* __restrict__ bv,
    bhalf_t* __restrict__ qo, bhalf_t* __restrict__ ko, bhalf_t* __restrict__ vto)
{
  __shared__ bhalf_t As[4096];
  __shared__ bhalf_t Bs[4096];
  const int seg = blockIdx.x >> 9;
  const int idx = blockIdx.x & 511;
  const int bm = idx & 63, bn = idx >> 6;    // XCD-aware: bm fast-varying

  const bhalf_t *A, *Bw; const float* bias; bhalf_t* out; float scale; int mode;
  if (seg == 0)      { A = Qb; Bw = Wqb; bias = bq; out = qo;  scale = 0.18033688f; mode = 0; }
  else if (seg == 1) { A = Kb; Bw = Wkb; bias = bk; out = ko;  scale = 1.0f;        mode = 0; }
  else               { A = Vb; Bw = Wvb; bias = bv; out = vto; scale = 1.0f;        mode = 1; }

  f32x4 acc[4][4];
#pragma unroll
  for (int i = 0; i < 4; ++i)
#pragma unroll
    for (int j = 0; j < 4; ++j)
      acc[i][j] = (f32x4){0.f, 0.f, 0.f, 0.f};

  gemm_core_128_swz(A, Bw, bm, bn, As, Bs, acc);

  const int lane = threadIdx.x & 63, wave = threadIdx.x >> 6;
  const int wm = wave >> 1, wn = wave & 1, quad = lane >> 4, tn = lane & 15;
#pragma unroll
  for (int i = 0; i < 4; ++i)
#pragma unroll
    for (int j = 0; j < 4; ++j) {
      const int n = bn * 128 + wn * 64 + j * 16 + tn;
      const float bsv = bias[n];
      const int h = n >> 6, dk = n & 63;
#pragma unroll
      for (int r = 0; r < 4; ++r) {
        const int m = bm * 128 + wm * 64 + i * 16 + quad * 4 + r;
        const int b = m >> 11, s = m & 2047;
        const float v = (acc[i][j][r] + bsv) * scale;
        size_t addr;
        if (mode == 0) addr = (((size_t)(b * 16 + h)) * 2048 + s) * 64 + dk;
        else {
          const int s2 = (s & ~12) | ((s & 4) << 1) | ((s & 8) >> 1);  // sigma
          addr = (((size_t)(b * 16 + h)) * 64 + dk) * 2048 + s2;
        }
        out[addr] = (bhalf_t)v;
      }
    }
}

// ---------------------------------------------------------------------------
__global__ __launch_bounds__(256) void out_gemm(
    const bhalf_t* __restrict__ A, const bhalf_t* __restrict__ Bw,
    const float* __restrict__ bias, float* __restrict__ Cout)
{
  __shared__ bhalf_t As[4096];
  __shared__ bhalf_t Bs[4096];
  const int bm = blockIdx.x & 63, bn = blockIdx.x >> 6;   // XCD-aware

  f32x4 acc[4][4];
#pragma unroll
  for (int i = 0; i < 4; ++i)
#pragma unroll
    for (int j = 0; j < 4; ++j)
      acc[i][j] = (f32x4){0.f, 0.f, 0.f, 0.f};

  gemm_core_128_swz(A, Bw, bm, bn, As, Bs, acc);

  const int lane = threadIdx.x & 63, wave = threadIdx.x >> 6;
  const int wm = wave >> 1, wn = wave & 1, quad = lane >> 4, tn = lane & 15;
#pragma unroll
  for (int i = 0; i < 4; ++i)
#pragma unroll
    for (int j = 0; j < 4; ++j) {
      const int n = bn * 128 + wn * 64 + j * 16 + tn;
      const float bsv = bias[n];
#pragma unroll
      for (int r = 0; r < 4; ++r) {
        const int m = bm * 128 + wm * 64 + i * 16 + quad * 4 + r;
        Cout[(size_t)m * 1024 + n] = acc[i][j][r] + bsv;
      }
    }
}

// ---------------------------------------------------------------------------
// Flash attention v3 (r6-verified config): dbuf K/Vt issue-early/drain-late,
// grid (64,8) -> XCD = bh%8 so all 8 qt-blocks of a bh share one XCD's L2,
// qt=256 (4 waves x 64 q rows).  NEW: s_setprio(1) around MFMA clusters
// (T5; regime = 2 independent blocks/CU drifting through phases, m191).
// ---------------------------------------------------------------------------
__global__ __launch_bounds__(256, 2) void attn_kernel(
    const bhalf_t* __restrict__ qp, const bhalf_t* __restrict__ kp,
    const bhalf_t* __restrict__ vtp, bhalf_t* __restrict__ outp)
{
  __shared__ bhalf_t Klds[2][4096];    // [64 kv][64 dk], XOR-swizzled chunks
  __shared__ bhalf_t Vtlds[2][4096];   // [64 dk][64 kv(sigma)], XOR-swizzled

  const int tid = threadIdx.x, lane = tid & 63, wave = tid >> 6;
  const int q31 = lane & 31, h = lane >> 5;
  const int bh = blockIdx.x, qt = blockIdx.y;   // XCD-local K/V sharing

  const bhalf_t* qbase = qp + (((size_t)bh * 2048) + qt * 256 + wave * 64 + q31) * 64;
  bf16x8 qf[2][4];
#pragma unroll
  for (int qs = 0; qs < 2; ++qs)
#pragma unroll
    for (int ks = 0; ks < 4; ++ks)
      qf[qs][ks] = *(const bf16x8*)(qbase + qs * 32 * 64 + ks * 16 + h * 8);

  f32x16 Ot[2][2];
#pragma unroll
  for (int qs = 0; qs < 2; ++qs)
#pragma unroll
    for (int dd = 0; dd < 2; ++dd)
#pragma unroll
      for (int i = 0; i < 16; ++i) Ot[qs][dd][i] = 0.f;
  float Lp[2] = {0.f, 0.f};

  const bhalf_t* kbase  = kp  + (size_t)bh * 2048 * 64;
  const bhalf_t* vtbase = vtp + (size_t)bh * 64 * 2048;

  const int rloc = lane >> 3;                 // staging row within 8-row chunk
  const int cg8  = ((lane & 7) ^ rloc) * 8;   // swizzled source chunk (elems)
  const int q7 = q31 & 7;

  // prologue: stage tile 0 into buffer 0
#pragma unroll
  for (int i = 0; i < 2; ++i) {
    const int r0 = (wave * 2 + i) * 8;
    GLD16(kbase + (size_t)(r0 + rloc) * 64 + cg8, &Klds[0][r0 * 64]);
    GLD16(vtbase + (size_t)(r0 + rloc) * 2048 + cg8, &Vtlds[0][r0 * 64]);
  }
  __syncthreads();

  for (int kv0 = 0; kv0 < 2048; kv0 += 64) {
    const int cur = (kv0 >> 6) & 1, nxt = cur ^ 1;
    if (kv0 < 2048 - 64) {   // issue next tile early (latency hides under compute)
#pragma unroll
      for (int i = 0; i < 2; ++i) {
        const int r0 = (wave * 2 + i) * 8;
        GLD16(kbase + (size_t)(kv0 + 64 + r0 + rloc) * 64 + cg8, &Klds[nxt][r0 * 64]);
        GLD16(vtbase + (size_t)(r0 + rloc) * 2048 + (kv0 + 64) + cg8, &Vtlds[nxt][r0 * 64]);
      }
    }
    const bhalf_t* Kc = Klds[cur];
    const bhalf_t* Vc = Vtlds[cur];

    // S^T + exp2 + pack into PV B-fragments (register-only)
    bf16x8 pb[2][4];
#pragma unroll
    for (int mb = 0; mb < 2; ++mb) {
      bf16x8 ka[4];
#pragma unroll
      for (int ks = 0; ks < 4; ++ks)
        ka[ks] = *(const bf16x8*)(Kc + (mb * 32 + q31) * 64 + ((2 * ks + h) ^ q7) * 8);
#pragma unroll
      for (int qs = 0; qs < 2; ++qs) {
        f32x16 S;
#pragma unroll
        for (int i = 0; i < 16; ++i) S[i] = 0.f;
        __builtin_amdgcn_s_setprio(1);
#pragma unroll
        for (int ks = 0; ks < 4; ++ks)
          S = __builtin_amdgcn_mfma_f32_32x32x16_bf16(ka[ks], qf[qs][ks], S, 0, 0, 0);
        __builtin_amdgcn_s_setprio(0);
        float ls = 0.f;
#pragma unroll
        for (int half = 0; half < 2; ++half) {
          bf16x8 pk;
#pragma unroll
          for (int j = 0; j < 8; ++j) {
            const float e = __builtin_amdgcn_exp2f(S[half * 8 + j]);
            ls += e;
            pk[j] = (bhalf_t)e;
          }
          pb[qs][mb * 2 + half] = pk;
        }
        Lp[qs] += ls;
      }
    }

    // O^T += Vt @ P
    __builtin_amdgcn_s_setprio(1);
#pragma unroll
    for (int dd = 0; dd < 2; ++dd)
#pragma unroll
      for (int kb = 0; kb < 4; ++kb) {
        const bf16x8 va = *(const bf16x8*)(Vc + (dd * 32 + q31) * 64 + ((2 * kb + h) ^ q7) * 8);
#pragma unroll
        for (int qs = 0; qs < 2; ++qs)
          Ot[qs][dd] = __builtin_amdgcn_mfma_f32_32x32x16_bf16(va, pb[qs][kb], Ot[qs][dd], 0, 0, 0);
      }
    __builtin_amdgcn_s_setprio(0);
    __syncthreads();   // drains vmcnt (next tile landed) + read-release of buf
  }

  const int b = bh >> 4, hh = bh & 15;
#pragma unroll
  for (int qs = 0; qs < 2; ++qs) {
    const float Lt = Lp[qs] + __shfl_xor(Lp[qs], 32, 64);
    const float linv = 1.0f / Lt;
    const int s = qt * 256 + wave * 64 + qs * 32 + q31;
    bhalf_t* ob = outp + ((size_t)(b * 2048 + s)) * 1024 + hh * 64;
#pragma unroll
    for (int dd = 0; dd < 2; ++dd)
#pragma unroll
      for (int g = 0; g < 4; ++g) {
        bf16x4 o;
        o.x = (bhalf_t)(Ot[qs][dd][4 * g + 0] * linv);
        o.y = (bhalf_t)(Ot[qs][dd][4 * g + 1] * linv);
        o.z = (bhalf_t)(Ot[qs][dd][4 * g + 2] * linv);
        o.w = (bhalf_t)(Ot[qs][dd][4 * g + 3] * linv);
        *(bf16x4*)(ob + dd * 32 + g * 8 + h * 4) = o;
      }
  }
}

// ---------------------------------------------------------------------------
extern "C" void kernel_launch(void* const* d_in, const int* in_sizes, int n_in,
                              void* d_out, int out_size, void* d_ws, size_t ws_size,
                              hipStream_t stream)
{
  const float* Q  = (const float*)d_in[0];
  const float* K  = (const float*)d_in[1];
  const float* V  = (const float*)d_in[2];
  const float* Wq = (const float*)d_in[3];
  const float* bq = (const float*)d_in[4];
  const float* Wk = (const float*)d_in[5];
  const float* bk = (const float*)d_in[6];
  const float* Wv = (const float*)d_in[7];
  const float* bv = (const float*)d_in[8];
  const float* Wo = (const float*)d_in[9];
  const float* bo = (const float*)d_in[10];

  char* ws = (char*)d_ws;
  const size_t SZ = 8192ull * 1024 * 2;   // 16 MB  [8192,1024] bf16
  const size_t WZ = 1024ull * 1024 * 2;   //  2 MB  [1024,1024] bf16
  bhalf_t* Qb   = (bhalf_t*)(ws);
  bhalf_t* Kb   = (bhalf_t*)(ws + SZ);
  bhalf_t* Vb   = (bhalf_t*)(ws + 2 * SZ);
  bhalf_t* Wqb  = (bhalf_t*)(ws + 3 * SZ);
  bhalf_t* Wkb  = (bhalf_t*)(ws + 3 * SZ + WZ);
  bhalf_t* Wvb  = (bhalf_t*)(ws + 3 * SZ + 2 * WZ);
  bhalf_t* Wob  = (bhalf_t*)(ws + 3 * SZ + 3 * WZ);
  bhalf_t* q_p  = (bhalf_t*)(ws + 3 * SZ + 4 * WZ);
  bhalf_t* k_p  = (bhalf_t*)(ws + 4 * SZ + 4 * WZ);
  bhalf_t* vt_p = (bhalf_t*)(ws + 5 * SZ + 4 * WZ);
  bhalf_t* attn_o = Qb;   // alias: Qb is dead after proj_gemm

  cvt_all<<<28672, 256, 0, stream>>>(Q, K, V, Wq, Wk, Wv, Wo,
                                     Qb, Kb, Vb, Wqb, Wkb, Wvb, Wob);
  proj_gemm<<<1536, 256, 0, stream>>>(Qb, Kb, Vb, Wqb, Wkb, Wvb,
                                      bq, bk, bv, q_p, k_p, vt_p);
  attn_kernel<<<dim3(64, 8), 256, 0, stream>>>(q_p, k_p, vt_p, attn_o);
  out_gemm<<<512, 256, 0, stream>>>(attn_o, Wob, bo, (float*)d_out);
}